// Round 1
// baseline (434.731 us; speedup 1.0000x reference)
//
#include <hip/hip_runtime.h>
#include <math.h>

// HybridBasisFunction: out = wavelet(x_clamped) + sigmoid(alpha) * spline(x_clamped)
// Elementwise over 64*4096*256 fp32 = 67,108,864 elements. Memory-bound:
// 512 MiB total HBM traffic -> ~85 us floor at 6.3 TB/s achievable.

__global__ __launch_bounds__(256) void hybrid_basis_kernel(
    const float4* __restrict__ x4,
    const float*  __restrict__ wc,     // 5 wavelet coeffs
    const float*  __restrict__ sc,     // 8 spline coeffs
    const float*  __restrict__ alpha,  // 1 scalar
    float4*       __restrict__ out4,
    int n4)
{
    // Stage the spline table in LDS: dynamic-index gather stays off VMEM/scratch.
    __shared__ float s_sc[8];
    if (threadIdx.x < 8) s_sc[threadIdx.x] = sc[threadIdx.x];

    // Uniform scalars (L1-cached broadcast loads).
    const float w0 = wc[0], w1 = wc[1], w2 = wc[2], w3 = wc[3], w4 = wc[4];
    const float sig = 1.0f / (1.0f + expf(-alpha[0]));
    __syncthreads();

    const int stride = gridDim.x * blockDim.x;
    for (int i = blockIdx.x * blockDim.x + threadIdx.x; i < n4; i += stride) {
        float4 v = x4[i];
        float in[4] = {v.x, v.y, v.z, v.w};
        float r[4];
        #pragma unroll
        for (int j = 0; j < 4; ++j) {
            float xc = fminf(fmaxf(in[j], 0.0f), 1.0f);

            // Wavelet: sign_l = +1 if frac(xc * 2^(l-1)) < 0.5 else -1, zero at xc==1.
            // Exact equivalence: frac(xc*2^(l-1)) < 0.5  <=>  bit (4-l) of
            // floor(xc*16) == 0 (power-of-2 scaling is exact in fp32).
            int u = (int)(xc * 16.0f);        // floor, xc >= 0
            bool interior = xc < 1.0f;
            float acc = w0;
            if (interior) {
                // Sequential adds: same association as reference.
                acc = acc + ((u & 8) ? -w1 : w1);
                acc = acc + ((u & 4) ? -w2 : w2);
                acc = acc + ((u & 2) ? -w3 : w3);
                acc = acc + ((u & 1) ? -w4 : w4);
            }

            // Linear spline: idx = xc*(grid-1), grid=5. k in [0,4], k+1 in [1,5] -> no clip needed.
            float idx = xc * 4.0f;            // exact (power of 2)
            int   k   = (int)idx;             // trunc == floor (idx >= 0)
            float ww  = idx - (float)k;       // exact
            float c0  = s_sc[k];
            float c1  = s_sc[k + 1];
            float sp  = c0 * (1.0f - ww) + c1 * ww;

            r[j] = acc + sig * sp;
        }
        out4[i] = make_float4(r[0], r[1], r[2], r[3]);
    }
}

extern "C" void kernel_launch(void* const* d_in, const int* in_sizes, int n_in,
                              void* d_out, int out_size, void* d_ws, size_t ws_size,
                              hipStream_t stream) {
    const float4* x4    = (const float4*)d_in[0];
    const float*  wc    = (const float*)d_in[1];
    const float*  sc    = (const float*)d_in[2];
    const float*  alpha = (const float*)d_in[3];
    float4*       out4  = (float4*)d_out;

    const int n  = in_sizes[0];          // 67,108,864
    const int n4 = n / 4;                // 16,777,216 float4s (divisible)

    // Grid-stride: 8192 blocks x 256 threads = 2M threads, 8 float4 each.
    // Plenty of waves to saturate 256 CUs for a streaming kernel.
    const int block = 256;
    const int grid  = 8192;
    hybrid_basis_kernel<<<grid, block, 0, stream>>>(x4, wc, sc, alpha, out4, n4);
}

// Round 2
// 421.517 us; speedup vs baseline: 1.0313x; 1.0313x over previous
//
#include <hip/hip_runtime.h>
#include <math.h>

// HybridBasisFunction: out = wavelet(x_clamped) + sigmoid(alpha) * spline(x_clamped)
// Elementwise over 64*4096*256 fp32 = 67,108,864 elements. Memory-bound:
// 512 MiB total HBM traffic -> ~85 us floor at 6.3 TB/s achievable.
//
// R2 changes vs R1 (435 us):
//  - LDS spline gather -> pure VALU v_cndmask select chain (6 live table
//    entries). Removes the per-element dependent ds_read pair + lgkmcnt waits.
//  - Grid-stride 8-iteration loop -> one thread per float4. One
//    global_load_dwordx4 + one global_store_dwordx4 per thread; 1M waves in
//    flight = maximal MLP for a pure stream.
//  - Branchless wavelet (single final select on interior).

__global__ __launch_bounds__(256) void hybrid_basis_kernel(
    const float4* __restrict__ x4,
    const float*  __restrict__ wc,     // 5 wavelet coeffs
    const float*  __restrict__ sc,     // 8 spline coeffs (only [0..5] reachable)
    const float*  __restrict__ alpha,  // 1 scalar
    float4*       __restrict__ out4,
    int n4)
{
    const int i = blockIdx.x * blockDim.x + threadIdx.x;
    if (i >= n4) return;

    // Uniform scalars -> s_load (scalar cache), broadcast to all lanes.
    const float w0 = wc[0], w1 = wc[1], w2 = wc[2], w3 = wc[3], w4 = wc[4];
    const float s0 = sc[0], s1 = sc[1], s2 = sc[2], s3 = sc[3], s4 = sc[4], s5 = sc[5];
    const float sig = 1.0f / (1.0f + expf(-alpha[0]));

    float4 v = x4[i];
    float in[4] = {v.x, v.y, v.z, v.w};
    float r[4];
    #pragma unroll
    for (int j = 0; j < 4; ++j) {
        float xc = fminf(fmaxf(in[j], 0.0f), 1.0f);

        // Wavelet: sign_l = +1 if frac(xc * 2^(l-1)) < 0.5 else -1, zero at
        // xc==1. frac(xc*2^(l-1)) < 0.5  <=>  bit (4-l) of floor(xc*16)==0
        // (power-of-2 scaling is exact in fp32). Branchless: compute the full
        // sum, then select w0-only for xc==1.0.
        int u = (int)(xc * 16.0f);        // floor, xc >= 0
        float acc = w0;
        acc = acc + ((u & 8) ? -w1 : w1);
        acc = acc + ((u & 4) ? -w2 : w2);
        acc = acc + ((u & 2) ? -w3 : w3);
        acc = acc + ((u & 1) ? -w4 : w4);
        acc = (xc < 1.0f) ? acc : w0;

        // Linear spline: idx = xc*4, k in [0,4]. Select c0 from s0..s4 and
        // c1 from s1..s5 with a shared compare chain (no LDS, no gather).
        float idx = xc * 4.0f;            // exact (power of 2)
        int   k   = (int)idx;             // trunc == floor (idx >= 0)
        float ww  = idx - (float)k;       // exact
        float c0 = s0, c1 = s1;
        if (k >= 1) { c0 = s1; c1 = s2; }
        if (k >= 2) { c0 = s2; c1 = s3; }
        if (k >= 3) { c0 = s3; c1 = s4; }
        if (k >= 4) { c0 = s4; c1 = s5; }
        float sp = c0 * (1.0f - ww) + c1 * ww;

        r[j] = acc + sig * sp;
    }
    out4[i] = make_float4(r[0], r[1], r[2], r[3]);
}

extern "C" void kernel_launch(void* const* d_in, const int* in_sizes, int n_in,
                              void* d_out, int out_size, void* d_ws, size_t ws_size,
                              hipStream_t stream) {
    const float4* x4    = (const float4*)d_in[0];
    const float*  wc    = (const float*)d_in[1];
    const float*  sc    = (const float*)d_in[2];
    const float*  alpha = (const float*)d_in[3];
    float4*       out4  = (float4*)d_out;

    const int n  = in_sizes[0];          // 67,108,864
    const int n4 = n / 4;                // 16,777,216 float4s (divisible)

    const int block = 256;
    const int grid  = (n4 + block - 1) / block;   // 65536 blocks
    hybrid_basis_kernel<<<grid, block, 0, stream>>>(x4, wc, sc, alpha, out4, n4);
}

// Round 3
// 418.539 us; speedup vs baseline: 1.0387x; 1.0071x over previous
//
#include <hip/hip_runtime.h>
#include <math.h>

// HybridBasisFunction: out = wavelet(xc) + sigmoid(alpha) * spline(xc), elementwise
// over 67,108,864 fp32. Memory floor: 512 MiB HBM traffic -> ~85 us at 6.3 TB/s.
//
// R3 theory: R2 was VALU-bound (~40 VALU ops/elem x 4 elem x 2 cyc = 320 cyc/wave
// vs 200-cyc HBM budget/wave). Fuse ALL per-element math into one LDS lookup:
//   u = floor(16*xc) in [0,16]
//   out = A[u] + B[u] * frac(4*xc)
//   A[u] = wavelet(u) + sig*sc[u>>2],  B[u] = sig*(sc[(u>>2)+1] - sc[u>>2])
// (u>>2 == floor(4*xc); frac(4*xc) == idx - k exactly; xc==1 -> u=16, frac=0,
//  A[16]=w0+sig*sc[4] which matches the reference's edge case.)
// Per element: ~6 VALU + 1 ds_read_b64 -> ~100 cyc/wave, under the memory budget.
// Table built once per block by lanes 0..16, overlapped with the streaming
// load's latency. Data is ~50% xc==0 / ~16% xc==1 -> LDS reads mostly
// same-address broadcast (free); distinct-address aliasing <= 2-way (free).

__global__ __launch_bounds__(256) void hybrid_basis_kernel(
    const float4* __restrict__ x4,
    const float*  __restrict__ wc,     // 5 wavelet coeffs
    const float*  __restrict__ sc,     // 8 spline coeffs (indices 0..5 reachable)
    const float*  __restrict__ alpha,  // 1 scalar
    float4*       __restrict__ out4,
    int n4)
{
    __shared__ float2 s_tab[17];

    const int i = blockIdx.x * blockDim.x + threadIdx.x;

    // Issue the streaming load FIRST; table setup hides under its latency.
    float4 v;
    if (i < n4) v = x4[i];

    const int u = threadIdx.x;
    if (u < 17) {
        // wc/sc/alpha are uniform-address loads (scalar cache).
        const float w1 = wc[1], w2 = wc[2], w3 = wc[3], w4 = wc[4];
        float wav = wc[0];
        if (u < 16) {   // u==16 (xc==1.0): wavelet contribution is wc[0] only
            wav += (u & 8) ? -w1 : w1;
            wav += (u & 4) ? -w2 : w2;
            wav += (u & 2) ? -w3 : w3;
            wav += (u & 1) ? -w4 : w4;
        }
        const float sig = 1.0f / (1.0f + expf(-alpha[0]));
        const int k = u >> 2;               // floor(4*xc) for this bucket, 0..4
        const float c0 = sc[k];
        const float c1 = sc[k + 1];         // k+1 <= 5, in bounds; B[16] is x0 anyway
        s_tab[u] = make_float2(wav + sig * c0, sig * (c1 - c0));
    }
    __syncthreads();

    if (i >= n4) return;

    const float in[4] = {v.x, v.y, v.z, v.w};
    float r[4];
    #pragma unroll
    for (int j = 0; j < 4; ++j) {
        const float xc = fminf(fmaxf(in[j], 0.0f), 1.0f);
        const int   uu = (int)(xc * 16.0f);       // exact: power-of-2 scale
        float       ww = xc * 4.0f;
        ww = ww - floorf(ww);                     // frac(4*xc) == idx - k exactly
        const float2 ab = s_tab[uu];              // one ds_read_b64
        r[j] = fmaf(ab.y, ww, ab.x);
    }
    out4[i] = make_float4(r[0], r[1], r[2], r[3]);
}

extern "C" void kernel_launch(void* const* d_in, const int* in_sizes, int n_in,
                              void* d_out, int out_size, void* d_ws, size_t ws_size,
                              hipStream_t stream) {
    const float4* x4    = (const float4*)d_in[0];
    const float*  wc    = (const float*)d_in[1];
    const float*  sc    = (const float*)d_in[2];
    const float*  alpha = (const float*)d_in[3];
    float4*       out4  = (float4*)d_out;

    const int n  = in_sizes[0];          // 67,108,864
    const int n4 = n / 4;                // 16,777,216 float4s

    const int block = 256;
    const int grid  = (n4 + block - 1) / block;   // 65536 blocks, exact fit
    hybrid_basis_kernel<<<grid, block, 0, stream>>>(x4, wc, sc, alpha, out4, n4);
}